// Round 11
// baseline (496.425 us; speedup 1.0000x reference)
//
#include <hip/hip_runtime.h>

#define NB 128
#define NTOK 201
#define EW 210   // u-slot holding the att-col-0 (e-column) weight

// Publish LDS writes across a barrier WITHOUT draining vmcnt: global loads
// issued before this stay in flight across the barrier.
__device__ __forceinline__ void lds_barrier() {
    asm volatile("s_waitcnt lgkmcnt(0)" ::: "memory");
    __builtin_amdgcn_s_barrier();
}

// u^T <- u^T * att_e[l], l = 10..0, u0 = row 0 of att_e[11].
// 256 threads = 64 col-groups (g: 4 padded cols via float4) x 4 waves
// (w: rows r === w mod 4). Padded-col space p = xcol-(lo-3), valid [3,M+2),
// e-weight at u[EW]. Per-wave 16B-aligned start col C_w ((b+row+col)%4==0,
// row stride 4*201 === 0 mod 4); per-wave col shift undone in the reduce.
// Rows r >= M clamp in-class (r-4), auto-masked by zero weight u[r+2].
// PF: rows of the NEXT layer prefetched into registers BEFORE barrier1, so
// their HBM latency hides under barrier1 + reduce + barrier2 (T14).
template<int M, int PF>
__device__ __forceinline__ void chain4(
    const float* __restrict__ xb, float* __restrict__ out,
    const int e, const int b, const int lo,
    float* u, float (*part)[212], float* rv, int* rix)
{
    constexpr int W4 = (M + 5) / 4;      // active float4 col-groups (50 / 26)
    constexpr int NK = (M + 3) / 4;      // rows per thread (50 / 25)

    const int tid = threadIdx.x;
    const int g   = tid & 63;
    const int w   = tid >> 6;            // wave index 0..3

    const size_t plane = (size_t)NTOK * NTOK;
    const float* L11 = xb + (size_t)(11 * NB) * plane + (size_t)e * NTOK;

    const int trg = (b + 2 * lo - 1 + w) & 3;
    const int C   = lo - trg;            // 16B-aligned start col for this wave

    // init u: zeros (clamp slots must stay 0), then valid slots
    if (tid < 212) u[tid] = 0.f;
    __syncthreads();
    if (tid >= 3 && tid < M + 2) u[tid] = L11[lo - 3 + tid];
    if (tid == EW)               u[tid] = L11[e];
    __syncthreads();

    const size_t rstep = (size_t)(4 * NTOK);
    const float* A = xb + (size_t)(10 * NB) * plane;

    float4 pf[PF];                       // chunk0 regs (g < W4 lanes)
    float  pfs[PF];                      // chunk0 regs (g == W4 lane)

    // prologue: prefetch chunk0 of layer 10
    if (g < W4) {
        const float* rp = A + (size_t)(lo - 1 + w) * NTOK + C + 4 * g;
        #pragma unroll
        for (int k = 0; k < PF; ++k) pf[k] = *(const float4*)(rp + rstep * k);
    } else if (g == W4) {
        const float* ep = A + (size_t)(lo - 1 + w) * NTOK + e;
        #pragma unroll
        for (int k = 0; k < PF; ++k) pfs[k] = ep[rstep * k];
    }

    for (int l = 10; l >= 0; --l) {
        const float* An = A - (size_t)NB * plane;
        if (g < W4) {
            float4 acc = make_float4(0.f, 0.f, 0.f, 0.f);
            if (w == 0) {                // att row 0 = x row e (head, wave 0 only)
                const float hw = u[EW];
                const float* hp = A + (size_t)e * NTOK + C + 4 * g;
                acc.x = hw * hp[0]; acc.y = hw * hp[1];
                acc.z = hw * hp[2]; acc.w = hw * hp[3];
            }
            // chunk0 from prefetched regs
            #pragma unroll
            for (int k = 0; k < PF; ++k) {
                const float wt = u[w + 2 + 4 * k];
                acc.x += wt * pf[k].x; acc.y += wt * pf[k].y;
                acc.z += wt * pf[k].z; acc.w += wt * pf[k].w;
            }
            // remaining rows loaded in-phase
            const float* rp = A + (size_t)(lo - 1 + w) * NTOK + C + 4 * g;
            #pragma unroll
            for (int k = PF; k < NK - 1; ++k) {
                const float wt = u[w + 2 + 4 * k];
                const float4 a = *(const float4*)(rp + rstep * k);
                acc.x += wt * a.x; acc.y += wt * a.y;
                acc.z += wt * a.z; acc.w += wt * a.w;
            }
            {   // tail row, in-class clamp for r >= M (zero weight there)
                constexpr int k = NK - 1;
                const int r = w + 4 * k;
                const float wt = u[r + 2];
                const float4 a = *(const float4*)(rp + rstep * k
                                                  - ((r >= M) ? rstep : 0));
                acc.x += wt * a.x; acc.y += wt * a.y;
                acc.z += wt * a.z; acc.w += wt * a.w;
            }
            if (l > 0) {                 // issue next layer's chunk0 BEFORE barrier1
                const float* rpn = An + (size_t)(lo - 1 + w) * NTOK + C + 4 * g;
                #pragma unroll
                for (int k = 0; k < PF; ++k) pf[k] = *(const float4*)(rpn + rstep * k);
            }
            *(float4*)&part[w][4 * g] = acc;
        } else if (g == W4) {            // the e-column (att col 0)
            float s = 0.f;
            if (w == 0) s = u[EW] * A[(size_t)e * NTOK + e];
            const float* ep = A + (size_t)(lo - 1 + w) * NTOK + e;
            #pragma unroll
            for (int k = 0; k < PF; ++k) s += u[w + 2 + 4 * k] * pfs[k];
            #pragma unroll
            for (int k = PF; k < NK - 1; ++k)
                s += u[w + 2 + 4 * k] * ep[rstep * k];
            {
                constexpr int k = NK - 1;
                const int r = w + 4 * k;
                s += u[r + 2] * ep[rstep * k - ((r >= M) ? rstep : 0)];
            }
            if (l > 0) {
                const float* epn = An + (size_t)(lo - 1 + w) * NTOK + e;
                #pragma unroll
                for (int k = 0; k < PF; ++k) pfs[k] = epn[rstep * k];
            }
            part[w][EW] = s;
        }
        lds_barrier();                   // publish part (prefetch stays in flight)
        // reduce 4 partials -> u (reads part, writes u: disjoint arrays)
        if (tid >= 3 && tid < M + 2) {
            float s = 0.f;
            #pragma unroll
            for (int q = 0; q < 4; ++q) {
                const int tq = (b + 2 * lo - 1 + q) & 3;
                s += part[q][tid - 3 + tq];   // undo per-wave col shift
            }
            u[tid] = s;
        } else if (tid == EW) {
            u[EW] = part[0][EW] + part[1][EW] + part[2][EW] + part[3][EW];
        }
        lds_barrier();                   // publish u / guard part reuse
        A = An;
    }

    // max + argmax over p in [3, M+2); p ascending == att-col ascending
    {
        float v = -INFINITY; int idx = 0x7fffffff;
        if (tid >= 3 && tid < M + 2) { v = u[tid]; idx = tid; }
        rv[tid] = v; rix[tid] = idx;
    }
    __syncthreads();
    for (int s = 128; s > 0; s >>= 1) {
        if (tid < s) {
            const float v2 = rv[tid + s]; const int i2 = rix[tid + s];
            if (v2 > rv[tid] || (v2 == rv[tid] && i2 < rix[tid])) {
                rv[tid] = v2; rix[tid] = i2;
            }
        }
        __syncthreads();
    }
    if (tid == 0) {
        out[e * NB + b]       = rv[0];
        out[640 + e * NB + b] = (float)(lo - 3 + rix[0]);   // = (j-1) + lo
    }
}

// bid = 128*e + b => bid%8 = b%8: all 5 chains of a batch on the SAME XCD
// (shared L2 dedups overlapping plane reads). 640 small blocks -> ~2.5
// independent chains/CU whose phases interleave (MLP across blocks).
__global__ __launch_bounds__(256, 4) void part_att_kernel(
    const float* __restrict__ x, float* __restrict__ out)
{
    __shared__ float u[212];
    __shared__ float part[4][212];
    __shared__ float rv[256];
    __shared__ int   rix[256];

    const int bid = blockIdx.x;
    const int e   = bid >> 7;
    const int b   = bid & 127;
    const float* xb = x + (size_t)b * ((size_t)NTOK * NTOK);

    if (e < 2) {
        chain4<197, 12>(xb, out, e, b, 5, u, part, rv, rix);
    } else {
        const int lo = (e == 2) ? 5 : (e == 3) ? 54 : 103;
        chain4<99, 6>(xb, out, e, b, lo, u, part, rv, rix);
    }
}

extern "C" void kernel_launch(void* const* d_in, const int* in_sizes, int n_in,
                              void* d_out, int out_size, void* d_ws, size_t ws_size,
                              hipStream_t stream) {
    (void)in_sizes; (void)n_in; (void)d_ws; (void)ws_size; (void)out_size;
    const float* x = (const float*)d_in[0];
    float* out = (float*)d_out;
    part_att_kernel<<<dim3(640), dim3(256), 0, stream>>>(x, out);
}

// Round 12
// 71.313 us; speedup vs baseline: 6.9612x; 6.9612x over previous
//
#include <hip/hip_runtime.h>

#define NB 128
#define NTOK 201
#define EW 210   // u-slot holding the att-col-0 (e-column) weight

// Publish LDS writes across a barrier WITHOUT draining vmcnt: global loads
// issued before this stay in flight across the barrier.
__device__ __forceinline__ void lds_barrier() {
    asm volatile("s_waitcnt lgkmcnt(0)" ::: "memory");
    __builtin_amdgcn_s_barrier();
}

// u^T <- u^T * att_e[l], l = 10..0, u0 = row 0 of att_e[11].
// 256 threads = 64 col-groups (g: 4 padded cols via float4) x 4 waves
// (w: rows r === w mod 4). Padded-col space p = xcol-(lo-3), valid [3,M+2),
// e-weight at u[EW]. Per-wave 16B-aligned start col C_w ((b+row+col)%4==0,
// row stride 4*201 === 0 mod 4); per-wave col shift undone in the reduce.
// Rows r >= M clamp in-class (r-4), auto-masked by zero weight u[r+2].
// Prefetch: rows k=0..3 of the NEXT layer live in named regs pf0..pf3 and are
// issued mid-FMA-phase, so they fly through {FMA tail, barrier, reduce,
// barrier} and the next layer starts without a load-latency stall.
template<int M>
__device__ __forceinline__ void chain4(
    const float* __restrict__ xb, float* __restrict__ out,
    const int e, const int b, const int lo,
    float* u, float (*part)[212], float* rv, int* rix)
{
    constexpr int W4 = (M + 5) / 4;      // active float4 col-groups (50 / 26)
    constexpr int NK = (M + 3) / 4;      // rows per thread (50 / 25)

    const int tid = threadIdx.x;
    const int g   = tid & 63;
    const int w   = tid >> 6;            // wave index 0..3

    const size_t plane = (size_t)NTOK * NTOK;
    const float* L11 = xb + (size_t)(11 * NB) * plane + (size_t)e * NTOK;

    const int trg = (b + 2 * lo - 1 + w) & 3;
    const int C   = lo - trg;            // 16B-aligned start col for this wave

    // init u: zeros (clamp slots must stay 0), then valid slots
    if (tid < 212) u[tid] = 0.f;
    __syncthreads();
    if (tid >= 3 && tid < M + 2) u[tid] = L11[lo - 3 + tid];
    if (tid == EW)               u[tid] = L11[e];
    __syncthreads();

    const size_t rstep = (size_t)(4 * NTOK);
    const float* A = xb + (size_t)(10 * NB) * plane;

    // named prefetch regs (rows k=0..3; r = w+4k <= w+12 < M always valid)
    float4 pf0, pf1, pf2, pf3;
    if (g < W4) {
        const float* rp = A + (size_t)(lo - 1 + w) * NTOK + C + 4 * g;
        pf0 = *(const float4*)(rp);
        pf1 = *(const float4*)(rp + rstep);
        pf2 = *(const float4*)(rp + 2 * rstep);
        pf3 = *(const float4*)(rp + 3 * rstep);
    }

    for (int l = 10; l >= 0; --l) {
        const float* An = A - (size_t)NB * plane;
        if (g < W4) {
            float4 acc = make_float4(0.f, 0.f, 0.f, 0.f);
            if (w == 0) {                // att row 0 = x row e (head, wave 0 only)
                const float hw = u[EW];
                const float* hp = A + (size_t)e * NTOK + C + 4 * g;
                acc.x = hw * hp[0]; acc.y = hw * hp[1];
                acc.z = hw * hp[2]; acc.w = hw * hp[3];
            }
            // consume prefetched rows k=0..3
            {
                float wt = u[w + 2];
                acc.x += wt * pf0.x; acc.y += wt * pf0.y;
                acc.z += wt * pf0.z; acc.w += wt * pf0.w;
                wt = u[w + 6];
                acc.x += wt * pf1.x; acc.y += wt * pf1.y;
                acc.z += wt * pf1.z; acc.w += wt * pf1.w;
                wt = u[w + 10];
                acc.x += wt * pf2.x; acc.y += wt * pf2.y;
                acc.z += wt * pf2.z; acc.w += wt * pf2.w;
                wt = u[w + 14];
                acc.x += wt * pf3.x; acc.y += wt * pf3.y;
                acc.z += wt * pf3.z; acc.w += wt * pf3.w;
            }
            // refill prefetch for the NEXT layer immediately (max flight time)
            if (l > 0) {
                const float* rpn = An + (size_t)(lo - 1 + w) * NTOK + C + 4 * g;
                pf0 = *(const float4*)(rpn);
                pf1 = *(const float4*)(rpn + rstep);
                pf2 = *(const float4*)(rpn + 2 * rstep);
                pf3 = *(const float4*)(rpn + 3 * rstep);
            }
            // in-phase rows k=4..NK-2
            const float* rp = A + (size_t)(lo - 1 + w) * NTOK + C + 4 * g;
            #pragma unroll
            for (int k = 4; k < NK - 1; ++k) {
                const float wt = u[w + 2 + 4 * k];
                const float4 a = *(const float4*)(rp + rstep * k);
                acc.x += wt * a.x; acc.y += wt * a.y;
                acc.z += wt * a.z; acc.w += wt * a.w;
            }
            {   // tail row, in-class clamp for r >= M (zero weight there)
                constexpr int k = NK - 1;
                const int r = w + 4 * k;
                const float wt = u[r + 2];
                const float4 a = *(const float4*)(rp + rstep * k
                                                  - ((r >= M) ? rstep : 0));
                acc.x += wt * a.x; acc.y += wt * a.y;
                acc.z += wt * a.z; acc.w += wt * a.w;
            }
            *(float4*)&part[w][4 * g] = acc;
        } else if (g == W4) {            // the e-column (att col 0), in-phase
            float s = 0.f;
            if (w == 0) s = u[EW] * A[(size_t)e * NTOK + e];
            const float* ep = A + (size_t)(lo - 1 + w) * NTOK + e;
            #pragma unroll
            for (int k = 0; k < NK - 1; ++k)
                s += u[w + 2 + 4 * k] * ep[rstep * k];
            {
                constexpr int k = NK - 1;
                const int r = w + 4 * k;
                s += u[r + 2] * ep[rstep * k - ((r >= M) ? rstep : 0)];
            }
            part[w][EW] = s;
        }
        lds_barrier();                   // publish part (prefetch stays in flight)
        // reduce 4 partials -> u (reads part, writes u: disjoint arrays)
        if (tid >= 3 && tid < M + 2) {
            float s = 0.f;
            #pragma unroll
            for (int q = 0; q < 4; ++q) {
                const int tq = (b + 2 * lo - 1 + q) & 3;
                s += part[q][tid - 3 + tq];   // undo per-wave col shift
            }
            u[tid] = s;
        } else if (tid == EW) {
            u[EW] = part[0][EW] + part[1][EW] + part[2][EW] + part[3][EW];
        }
        lds_barrier();                   // publish u / guard part reuse
        A = An;
    }

    // max + argmax over p in [3, M+2); p ascending == att-col ascending
    {
        float v = -INFINITY; int idx = 0x7fffffff;
        if (tid >= 3 && tid < M + 2) { v = u[tid]; idx = tid; }
        rv[tid] = v; rix[tid] = idx;
    }
    __syncthreads();
    for (int s = 128; s > 0; s >>= 1) {
        if (tid < s) {
            const float v2 = rv[tid + s]; const int i2 = rix[tid + s];
            if (v2 > rv[tid] || (v2 == rv[tid] && i2 < rix[tid])) {
                rv[tid] = v2; rix[tid] = i2;
            }
        }
        __syncthreads();
    }
    if (tid == 0) {
        out[e * NB + b]       = rv[0];
        out[640 + e * NB + b] = (float)(lo - 3 + rix[0]);   // = (j-1) + lo
    }
}

// bid = 128*e + b => bid%8 = b%8: all 5 chains of a batch on the SAME XCD
// (shared L2 dedups overlapping plane reads). 640 small blocks -> ~2.5
// independent chains/CU whose phases interleave (MLP across blocks).
__global__ __launch_bounds__(256) void part_att_kernel(
    const float* __restrict__ x, float* __restrict__ out)
{
    __shared__ float u[212];
    __shared__ float part[4][212];
    __shared__ float rv[256];
    __shared__ int   rix[256];

    const int bid = blockIdx.x;
    const int e   = bid >> 7;
    const int b   = bid & 127;
    const float* xb = x + (size_t)b * ((size_t)NTOK * NTOK);

    if (e < 2) {
        chain4<197>(xb, out, e, b, 5, u, part, rv, rix);
    } else {
        const int lo = (e == 2) ? 5 : (e == 3) ? 54 : 103;
        chain4<99>(xb, out, e, b, lo, u, part, rv, rix);
    }
}

extern "C" void kernel_launch(void* const* d_in, const int* in_sizes, int n_in,
                              void* d_out, int out_size, void* d_ws, size_t ws_size,
                              hipStream_t stream) {
    (void)in_sizes; (void)n_in; (void)d_ws; (void)ws_size; (void)out_size;
    const float* x = (const float*)d_in[0];
    float* out = (float*)d_out;
    part_att_kernel<<<dim3(640), dim3(256), 0, stream>>>(x, out);
}

// Round 13
// 46.334 us; speedup vs baseline: 10.7140x; 1.5391x over previous
//
#include <hip/hip_runtime.h>

#define NB 128
#define NTOK 201
#define EW 210   // u-slot holding the att-col-0 (e-column) weight

// Publish LDS writes across a barrier WITHOUT draining vmcnt.
__device__ __forceinline__ void lds_barrier() {
    asm volatile("s_waitcnt lgkmcnt(0)" ::: "memory");
    __builtin_amdgcn_s_barrier();
}

// u^T <- u^T * att_e[l], l = 10..0, u0 = row 0 of att_e[11].
// 256 threads = 64 col-groups (g) x 4 waves (w: rows r === w mod 4).
// Padded-col space p = xcol-(lo-3), valid [3,M+2), e-weight at u[EW].
// Per-wave 16B-aligned start col C_w; per-wave col shift undone in the reduce.
// Rows r >= M clamp in-class (r-4), auto-masked by zero weight u[r+2].
// e-column FOLDED into the float4 loop: lane g==W4 runs the same loop with
// quad base col0 = e - sel (aligned in-class, col e at component sel), so the
// wave no longer serially executes a second scalar loop for the e-column.
template<int M>
__device__ __forceinline__ void chain4(
    const float* __restrict__ xb, float* __restrict__ out,
    const int e, const int b, const int lo,
    float* u, float (*part)[212], float* rv, int* rix)
{
    constexpr int W4 = (M + 5) / 4;      // active float4 col-groups (50 / 26)
    constexpr int NK = (M + 3) / 4;      // rows per thread (50 / 25)

    const int tid = threadIdx.x;
    const int g   = tid & 63;
    const int w   = tid >> 6;            // wave index 0..3

    const size_t plane = (size_t)NTOK * NTOK;
    const float* L11 = xb + (size_t)(11 * NB) * plane + (size_t)e * NTOK;

    const int trg = (b + 2 * lo - 1 + w) & 3;
    const int C   = lo - trg;            // 16B-aligned start col for this wave
    const int sel = (b + lo - 1 + w + e) & 3;   // col e's component in lane-W4 quads
    // lane base col: window quad for g<W4; e-containing aligned quad for g==W4
    const int col0 = (g < W4) ? (C + 4 * g) : (e - sel);

    // init u: zeros (clamp slots must stay 0), then valid slots
    if (tid < 212) u[tid] = 0.f;
    __syncthreads();
    if (tid >= 3 && tid < M + 2) u[tid] = L11[lo - 3 + tid];
    if (tid == EW)               u[tid] = L11[e];
    __syncthreads();

    const size_t rstep = (size_t)(4 * NTOK);
    const float* A = xb + (size_t)(10 * NB) * plane;

    for (int l = 10; l >= 0; --l) {
        if (g <= W4) {
            float4 acc = make_float4(0.f, 0.f, 0.f, 0.f);
            float shead = 0.f;
            if (w == 0) {                // att row 0 = x row e (wave 0 only)
                const float hw = u[EW];
                if (g < W4) {
                    const float* hp = A + (size_t)e * NTOK + col0;
                    acc.x = hw * hp[0]; acc.y = hw * hp[1];
                    acc.z = hw * hp[2]; acc.w = hw * hp[3];
                } else {                 // scalar head: avoids OOB quad at e=0
                    shead = hw * A[(size_t)e * NTOK + e];
                }
            }
            const float* rp = A + (size_t)(lo - 1 + w) * NTOK + col0;
            #pragma unroll
            for (int k = 0; k < NK - 1; ++k) {
                const float wt = u[w + 2 + 4 * k];
                const float4 a = *(const float4*)(rp + rstep * k);
                acc.x += wt * a.x; acc.y += wt * a.y;
                acc.z += wt * a.z; acc.w += wt * a.w;
            }
            {   // tail row, in-class clamp for r >= M (zero weight there)
                constexpr int k = NK - 1;
                const int r = w + 4 * k;
                const float wt = u[r + 2];
                const float4 a = *(const float4*)(rp + rstep * k
                                                  - ((r >= M) ? rstep : 0));
                acc.x += wt * a.x; acc.y += wt * a.y;
                acc.z += wt * a.z; acc.w += wt * a.w;
            }
            if (g < W4) {
                *(float4*)&part[w][4 * g] = acc;
            } else {
                const float se = (sel == 0) ? acc.x :
                                 (sel == 1) ? acc.y :
                                 (sel == 2) ? acc.z : acc.w;
                part[w][EW] = se + shead;
            }
        }
        lds_barrier();                   // publish part
        // reduce 4 partials -> u (reads part, writes u: disjoint arrays)
        if (tid >= 3 && tid < M + 2) {
            float s = 0.f;
            #pragma unroll
            for (int q = 0; q < 4; ++q) {
                const int tq = (b + 2 * lo - 1 + q) & 3;
                s += part[q][tid - 3 + tq];   // undo per-wave col shift
            }
            u[tid] = s;
        } else if (tid == EW) {
            u[EW] = part[0][EW] + part[1][EW] + part[2][EW] + part[3][EW];
        }
        lds_barrier();                   // publish u / guard part reuse
        A -= (size_t)NB * plane;
    }

    // max + argmax over p in [3, M+2); p ascending == att-col ascending
    {
        float v = -INFINITY; int idx = 0x7fffffff;
        if (tid >= 3 && tid < M + 2) { v = u[tid]; idx = tid; }
        rv[tid] = v; rix[tid] = idx;
    }
    __syncthreads();
    for (int s = 128; s > 0; s >>= 1) {
        if (tid < s) {
            const float v2 = rv[tid + s]; const int i2 = rix[tid + s];
            if (v2 > rv[tid] || (v2 == rv[tid] && i2 < rix[tid])) {
                rv[tid] = v2; rix[tid] = i2;
            }
        }
        __syncthreads();
    }
    if (tid == 0) {
        out[e * NB + b]       = rv[0];
        out[640 + e * NB + b] = (float)(lo - 3 + rix[0]);   // = (j-1) + lo
    }
}

// bid = 128*e + b => bid%8 = b%8: all 5 chains of a batch on the SAME XCD
// (shared L2 dedups overlapping plane reads). 640 small blocks -> ~2.5
// independent chains/CU whose phases interleave (MLP across blocks).
__global__ __launch_bounds__(256, 4) void part_att_kernel(
    const float* __restrict__ x, float* __restrict__ out)
{
    __shared__ float u[212];
    __shared__ float part[4][212];
    __shared__ float rv[256];
    __shared__ int   rix[256];

    const int bid = blockIdx.x;
    const int e   = bid >> 7;
    const int b   = bid & 127;
    const float* xb = x + (size_t)b * ((size_t)NTOK * NTOK);

    if (e < 2) {
        chain4<197>(xb, out, e, b, 5, u, part, rv, rix);
    } else {
        const int lo = (e == 2) ? 5 : (e == 3) ? 54 : 103;
        chain4<99>(xb, out, e, b, lo, u, part, rv, rix);
    }
}

extern "C" void kernel_launch(void* const* d_in, const int* in_sizes, int n_in,
                              void* d_out, int out_size, void* d_ws, size_t ws_size,
                              hipStream_t stream) {
    (void)in_sizes; (void)n_in; (void)d_ws; (void)ws_size; (void)out_size;
    const float* x = (const float*)d_in[0];
    float* out = (float*)d_out;
    part_att_kernel<<<dim3(640), dim3(256), 0, stream>>>(x, out);
}